// Round 9
// baseline (4318.292 us; speedup 1.0000x reference)
//
#include <hip/hip_runtime.h>

#define NUM_USERS 100000
#define NUM_ITEMS 50000
#define NNODES    150000
#define EMB       64
#define NEDGES    4800000
#define BATCH     4096
#define BUCKETS   293           // 512-row buckets (293*512 = 150016 >= NNODES)
#define EPB       8192          // edges per binA block
#define NBLK_A    586           // ceil(NEDGES/EPB)
#define CAP       17408         // per-bucket tmp capacity (mean 16382, +8 sigma)
#define INIT_BLKS 2344          // ceil(2.4M float4-units / 1024)
#define NSAMP     (3 * BATCH)   // sampled slots for layer 3
#define MCAP      128           // per-slot minilist capacity (deg mean 32)

typedef unsigned short u16;
typedef unsigned int   u32;

__device__ inline float bf2f(u16 u) { return __uint_as_float(((u32)u) << 16); }
__device__ inline u16 f2bf(float f) {                 // RNE
    u32 b = __float_as_uint(f);
    b += 0x7FFFu + ((b >> 16) & 1u);
    return (u16)(b >> 16);
}
__device__ inline u32 pack2(float a, float b) {
    return (u32)f2bf(a) | ((u32)f2bf(b) << 16);
}

__device__ inline void init_body(const float* __restrict__ user_emb,
                                 const float* __restrict__ item_emb,
                                 u16* __restrict__ l0, long i) {
    const long n4 = (long)NNODES * EMB / 4;
    if (i >= n4) return;
    const long nu4 = (long)NUM_USERS * EMB / 4;
    float4 v = (i < nu4) ? ((const float4*)user_emb)[i]
                         : ((const float4*)item_emb)[i - nu4];
    ushort4 o;
    o.x = f2bf(v.x); o.y = f2bf(v.y); o.z = f2bf(v.z); o.w = f2bf(v.w);
    ((ushort4*)l0)[i] = o;
}

// node -> canonical sampled slot (atomicMin over duplicates)
__global__ void slot_build(const int* __restrict__ users,
                           const int* __restrict__ pos_items,
                           const int* __restrict__ neg_items,
                           int* __restrict__ slotmap) {
    int s = blockIdx.x * blockDim.x + threadIdx.x;
    if (s >= NSAMP) return;
    int node;
    if (s < BATCH)          node = users[s];
    else if (s < 2 * BATCH) node = pos_items[s - BATCH] + NUM_USERS;
    else                    node = neg_items[s - 2 * BATCH] + NUM_USERS;
    atomicMin(&slotmap[node], s);
}

// --- Pass A: LDS bucket histogram (rows in regs) -> parallel per-bucket
// global reservation -> direct scatter to bucket-chunked tmp. Sampled-row
// edges also appended to per-slot minilist. Fused init blocks ride along.
// pack.x = (rowLocal<<18) | col   (col < 2^18, rowLocal < 512)
__global__ void __launch_bounds__(512) binA_kernel(const int* __restrict__ rows,
                                                   const int* __restrict__ cols,
                                                   const float* __restrict__ vals,
                                                   int* __restrict__ bfill,
                                                   int2* __restrict__ tmp,
                                                   const int* __restrict__ slotmap,
                                                   int* __restrict__ mfill,
                                                   int2* __restrict__ minilist,
                                                   const float* __restrict__ uemb,
                                                   const float* __restrict__ iemb,
                                                   u16* __restrict__ l0) {
    if (blockIdx.x >= NBLK_A) {                     // fused init blocks
        long ib = blockIdx.x - NBLK_A;
        long i = ib * 1024 + threadIdx.x;
        init_body(uemb, iemb, l0, i);
        init_body(uemb, iemb, l0, i + 512);
        return;
    }
    __shared__ int hist[BUCKETS];
    __shared__ int cursor[BUCKETS];
    const int tid = threadIdx.x;
    for (int i = tid; i < BUCKETS; i += 512) hist[i] = 0;
    __syncthreads();

    const long base = (long)blockIdx.x * EPB;
    int rsave[16];                                  // rows read ONCE, kept in regs
    #pragma unroll
    for (int k = 0; k < 16; ++k) {
        long e = base + (long)k * 512 + tid;
        int r = -1;
        if (e < NEDGES) {
            r = rows[e];
            atomicAdd(&hist[r >> 9], 1);
        }
        rsave[k] = r;
    }
    __syncthreads();

    // one global atomic per non-empty (block,bucket), all threads in parallel
    for (int b = tid; b < BUCKETS; b += 512) {
        int h = hist[b];
        cursor[b] = h ? b * CAP + atomicAdd(&bfill[b], h) : 0;
    }
    __syncthreads();

    #pragma unroll
    for (int k = 0; k < 16; ++k) {
        int r = rsave[k];
        if (r >= 0) {
            long e = base + (long)k * 512 + tid;
            int c = cols[e];
            int vb = __float_as_int(vals[e]);
            int pos = atomicAdd(&cursor[r >> 9], 1);
            tmp[pos] = make_int2(((r & 511) << 18) | c, vb);
            int s = slotmap[r];
            if (s < NSAMP) {                        // sampled row: minilist append
                int mp = atomicAdd(&mfill[s], 1);
                if (mp < MCAP) minilist[(long)s * MCAP + mp] = make_int2(c, vb);
            }
        }
    }
}

// --- SpMM, bucket-push: one block per HALF-bucket (256 rows). 64 KB LDS
// fp32 accumulator; stream bucket edges; gather x[col]; LDS atomic add with
// row-rotated dim layout (bank spread); dense bf16 writeout.
__global__ void __launch_bounds__(1024) spmm_bucket(const int* __restrict__ bfill,
                                                    const int2* __restrict__ tmp,
                                                    const u16* __restrict__ cur,
                                                    u16* __restrict__ nxt) {
    __shared__ float acc[256 * EMB];                // 64 KB
    const int bucket = blockIdx.x >> 1;
    const int half   = blockIdx.x & 1;
    const int tid = threadIdx.x;
    for (int i = tid; i < 256 * EMB; i += 1024) acc[i] = 0.f;
    __syncthreads();

    const int cnt = bfill[bucket];
    const int2* src = tmp + (long)bucket * CAP;
    const int t = tid & 7;                          // dim-slice lane

    int k = tid >> 3;                               // 128 groups of 8 lanes
    while (k < cnt) {
        int k1 = k + 128;
        int2 e0 = src[k];
        int2 e1 = (k1 < cnt) ? src[k1] : make_int2(-1, 0);
        bool g0 = ((e0.x >> 26) & 1) == half;
        bool g1 = (k1 < cnt) && (((e1.x >> 26) & 1) == half);
        uint4 x0, x1;
        if (g0) x0 = *(const uint4*)(cur + ((long)(e0.x & 0x3FFFF) << 6) + (t << 3));
        if (g1) x1 = *(const uint4*)(cur + ((long)(e1.x & 0x3FFFF) << 6) + (t << 3));
        if (g0) {
            int rl = (e0.x >> 18) & 255;
            float v = __int_as_float(e0.y);
            int rb = rl << 6;
            u32 w[4] = {x0.x, x0.y, x0.z, x0.w};
            #pragma unroll
            for (int j = 0; j < 4; ++j) {
                int d = (t << 3) + (j << 1);
                atomicAdd(&acc[rb + ((d + rl) & 63)],     v * __uint_as_float(w[j] << 16));
                atomicAdd(&acc[rb + ((d + 1 + rl) & 63)], v * __uint_as_float(w[j] & 0xFFFF0000u));
            }
        }
        if (g1) {
            int rl = (e1.x >> 18) & 255;
            float v = __int_as_float(e1.y);
            int rb = rl << 6;
            u32 w[4] = {x1.x, x1.y, x1.z, x1.w};
            #pragma unroll
            for (int j = 0; j < 4; ++j) {
                int d = (t << 3) + (j << 1);
                atomicAdd(&acc[rb + ((d + rl) & 63)],     v * __uint_as_float(w[j] << 16));
                atomicAdd(&acc[rb + ((d + 1 + rl) & 63)], v * __uint_as_float(w[j] & 0xFFFF0000u));
            }
        }
        k += 256;
    }
    __syncthreads();

    // writeout: 256 rows x 64 dims; thread -> (row = tid>>2, 16 dims)
    int lr = tid >> 2;
    long gRow = (long)bucket * 512 + half * 256 + lr;
    if (gRow < NNODES) {
        int dimBase = (tid & 3) << 4;
        u32 w8[8];
        #pragma unroll
        for (int d = 0; d < 16; d += 2) {
            float f0 = acc[(lr << 6) + ((dimBase + d + lr) & 63)];
            float f1 = acc[(lr << 6) + ((dimBase + d + 1 + lr) & 63)];
            w8[d >> 1] = pack2(f0, f1);
        }
        uint4* dst = (uint4*)(nxt + (gRow << 6) + dimBase);
        dst[0] = make_uint4(w8[0], w8[1], w8[2], w8[3]);
        dst[1] = make_uint4(w8[4], w8[5], w8[6], w8[7]);
    }
}

#define ACCX(V, X) { \
    a[0] += (V) * __uint_as_float((X).x << 16); \
    a[1] += (V) * __uint_as_float((X).x & 0xFFFF0000u); \
    a[2] += (V) * __uint_as_float((X).y << 16); \
    a[3] += (V) * __uint_as_float((X).y & 0xFFFF0000u); \
    a[4] += (V) * __uint_as_float((X).z << 16); \
    a[5] += (V) * __uint_as_float((X).z & 0xFFFF0000u); \
    a[6] += (V) * __uint_as_float((X).w << 16); \
    a[7] += (V) * __uint_as_float((X).w & 0xFFFF0000u); }

// Layer 3 at sampled slots from the minilist. Output fp32 [NSAMP][64].
// Non-canonical slots have mfill==0 -> zeros (never read by score).
__global__ void spmm_sampled(const int* __restrict__ mfill,
                             const int2* __restrict__ minilist,
                             const u16* __restrict__ cur, float* __restrict__ sampled) {
    int gtid = blockIdx.x * blockDim.x + threadIdx.x;
    int slot = gtid >> 3;
    int t    = gtid & 7;
    if (slot >= NSAMP) return;
    int cnt = mfill[slot];
    if (cnt > MCAP) cnt = MCAP;
    const int2* src = minilist + (long)slot * MCAP;
    float a[8];
    #pragma unroll
    for (int i = 0; i < 8; ++i) a[i] = 0.f;

    int e = 0;
    for (; e + 3 < cnt; e += 4) {
        int2 p[4];
        #pragma unroll
        for (int j = 0; j < 4; ++j) p[j] = src[e + j];
        uint4 x[4];
        #pragma unroll
        for (int j = 0; j < 4; ++j)
            x[j] = *(const uint4*)(cur + ((long)p[j].x << 6) + (t << 3));
        #pragma unroll
        for (int j = 0; j < 4; ++j) {
            float v = __int_as_float(p[j].y);
            ACCX(v, x[j]);
        }
    }
    for (; e < cnt; ++e) {
        int2 p = src[e];
        float v = __int_as_float(p.y);
        uint4 x = *(const uint4*)(cur + ((long)p.x << 6) + (t << 3));
        ACCX(v, x);
    }

    float4* dst = (float4*)(sampled + ((long)slot << 6) + (t << 3));
    dst[0] = make_float4(a[0], a[1], a[2], a[3]);
    dst[1] = make_float4(a[4], a[5], a[6], a[7]);
}

// One wave per batch element; lane = embedding dim.
// final = (emb + l1 + l2 + l3)/4 -> dot scaled by 1/16. l3 via slotmap.
__global__ void score_kernel(const int* __restrict__ users,
                             const int* __restrict__ pos_items,
                             const int* __restrict__ neg_items,
                             const float* __restrict__ uemb,
                             const float* __restrict__ iemb,
                             const u16* __restrict__ l1,
                             const u16* __restrict__ l2,
                             const int* __restrict__ slotmap,
                             const float* __restrict__ sampled,
                             float* __restrict__ out) {
    int gtid = blockIdx.x * blockDim.x + threadIdx.x;
    int wave = gtid >> 6;
    int lane = threadIdx.x & 63;
    if (wave >= BATCH) return;
    int u = users[wave];
    int p = pos_items[wave];
    int n = neg_items[wave];
    int un = u, pn = p + NUM_USERS, nn = n + NUM_USERS;
    long U = (long)un * EMB + lane;
    long P = (long)pn * EMB + lane;
    long N = (long)nn * EMB + lane;
    float ue = uemb[(long)u * EMB + lane] + bf2f(l1[U]) + bf2f(l2[U])
             + sampled[(long)slotmap[un] * EMB + lane];
    float pe = iemb[(long)p * EMB + lane] + bf2f(l1[P]) + bf2f(l2[P])
             + sampled[(long)slotmap[pn] * EMB + lane];
    float ne = iemb[(long)n * EMB + lane] + bf2f(l1[N]) + bf2f(l2[N])
             + sampled[(long)slotmap[nn] * EMB + lane];
    float ps = ue * pe;
    float ns = ue * ne;
    #pragma unroll
    for (int off = 32; off > 0; off >>= 1) {
        ps += __shfl_down(ps, off, 64);
        ns += __shfl_down(ns, off, 64);
    }
    if (lane == 0) {
        out[wave]         = ps * 0.0625f;
        out[BATCH + wave] = ns * 0.0625f;
    }
}

extern "C" void kernel_launch(void* const* d_in, const int* in_sizes, int n_in,
                              void* d_out, int out_size, void* d_ws, size_t ws_size,
                              hipStream_t stream) {
    const int*   users = (const int*)d_in[0];
    const int*   pos   = (const int*)d_in[1];
    const int*   neg   = (const int*)d_in[2];
    const int*   rows  = (const int*)d_in[3];
    const int*   cols  = (const int*)d_in[4];
    const float* vals  = (const float*)d_in[5];
    const float* uemb  = (const float*)d_in[6];
    const float* iemb  = (const float*)d_in[7];
    float* out = (float*)d_out;

    const size_t tblElems = (size_t)NNODES * EMB;       // bf16 elems, 19.2 MB each
    u16*  B0       = (u16*)d_ws;                        // l0
    u16*  B1       = B0 + tblElems;                     // l1
    u16*  B2       = B1 + tblElems;                     // l2
    int2* tmp      = (int2*)(B2 + tblElems);            // BUCKETS*CAP int2 = 40.8 MB
    int2* minilist = tmp + (size_t)BUCKETS * CAP;       // NSAMP*MCAP int2 = 12.6 MB
    float* sampled = (float*)(minilist + (size_t)NSAMP * MCAP);  // 3.1 MB
    int*  slotmap  = (int*)(sampled + (size_t)NSAMP * EMB);      // NNODES ints
    int*  bfill    = slotmap + NNODES;                  // 320 (pad)
    int*  mfill    = bfill + 320;                       // NSAMP ints
    // total ~115 MB (round 2 already used ~190 MB of ws successfully)

    hipMemsetAsync(bfill, 0, (320 + NSAMP) * sizeof(int), stream);   // bfill+mfill
    hipMemsetAsync(slotmap, 0x7F, NNODES * sizeof(int), stream);     // "no slot"

    slot_build<<<(NSAMP + 255) / 256, 256, 0, stream>>>(users, pos, neg, slotmap);

    // bin edges (+fused l0 init)
    binA_kernel<<<NBLK_A + INIT_BLKS, 512, 0, stream>>>(rows, cols, vals, bfill, tmp,
                                                        slotmap, mfill, minilist,
                                                        uemb, iemb, B0);

    // layers 1,2 full (bucket-push, LDS accum); layer 3 at sampled slots
    spmm_bucket<<<BUCKETS * 2, 1024, 0, stream>>>(bfill, tmp, B0, B1);
    spmm_bucket<<<BUCKETS * 2, 1024, 0, stream>>>(bfill, tmp, B1, B2);
    spmm_sampled<<<(NSAMP * 8 + 255) / 256, 256, 0, stream>>>(mfill, minilist, B2, sampled);

    score_kernel<<<(BATCH * 64) / 256, 256, 0, stream>>>(users, pos, neg,
                                                         uemb, iemb, B1, B2,
                                                         slotmap, sampled, out);
}

// Round 10
// 456.500 us; speedup vs baseline: 9.4596x; 9.4596x over previous
//
#include <hip/hip_runtime.h>

#define NUM_USERS 100000
#define NUM_ITEMS 50000
#define NNODES    150000
#define EMB       64
#define NEDGES    4800000
#define BATCH     4096
#define BUCKETS   293           // 512-row buckets (293*512 = 150016 >= NNODES)
#define BROWS     512
#define EPB       8192          // edges per binA block
#define NBLK_A    586           // ceil(NEDGES/EPB)
#define CAP       17408         // per-bucket tmp capacity (mean 16382, +8 sigma)
#define NSAMP     (3 * BATCH)   // sampled rows for layer 3

typedef unsigned short u16;
typedef unsigned int   u32;

__device__ inline float bf2f(u16 u) { return __uint_as_float(((u32)u) << 16); }
__device__ inline u16 f2bf(float f) {                 // RNE
    u32 b = __float_as_uint(f);
    b += 0x7FFFu + ((b >> 16) & 1u);
    return (u16)(b >> 16);
}
__device__ inline u32 pack2(float a, float b) {
    return (u32)f2bf(a) | ((u32)f2bf(b) << 16);
}

// l0 init: concat(user_emb, item_emb) -> bf16 table.
__global__ void init_kernel(const float* __restrict__ user_emb,
                            const float* __restrict__ item_emb,
                            u16* __restrict__ l0) {
    long i = (long)blockIdx.x * blockDim.x + threadIdx.x;   // float4 units
    const long n4 = (long)NNODES * EMB / 4;
    if (i >= n4) return;
    const long nu4 = (long)NUM_USERS * EMB / 4;
    float4 v = (i < nu4) ? ((const float4*)user_emb)[i]
                         : ((const float4*)item_emb)[i - nu4];
    ushort4 o;
    o.x = f2bf(v.x); o.y = f2bf(v.y); o.z = f2bf(v.z); o.w = f2bf(v.w);
    ((ushort4*)l0)[i] = o;
}

// --- Pass A v3: LDS hist (rows in regs) -> LDS scan -> PARALLEL global
// reservations (latency overlapped with LDS scatter) -> LDS bucket-sort ->
// per-wave BURST flush of whole slices (contiguous dword stores).
// pack.x = (rowLocal<<18) | col   (col < 2^18, rowLocal < 512)
__global__ void __launch_bounds__(512) binA_kernel(const int* __restrict__ rows,
                                                   const int* __restrict__ cols,
                                                   const float* __restrict__ vals,
                                                   int* __restrict__ bfill,
                                                   int2* __restrict__ tmp) {
    __shared__ int2 ebuf[EPB];                 // 64 KB bucket-sorted edges
    __shared__ int  hist[BUCKETS];
    __shared__ int  start[BUCKETS];
    __shared__ int  cursor[BUCKETS];
    __shared__ int  gbase[BUCKETS];
    const int tid = threadIdx.x;
    for (int i = tid; i < BUCKETS; i += 512) hist[i] = 0;
    __syncthreads();

    const long base = (long)blockIdx.x * EPB;
    int rsave[16];                              // rows read ONCE, kept in regs
    #pragma unroll
    for (int k = 0; k < 16; ++k) {
        long e = base + (long)k * 512 + tid;
        int r = -1;
        if (e < NEDGES) {
            r = rows[e];
            atomicAdd(&hist[r >> 9], 1);
        }
        rsave[k] = r;
    }
    __syncthreads();

    // exclusive scan hist -> start/cursor (wave 0, 64-chunks with carry)
    if (tid < 64) {
        int carry = 0;
        for (int cb = 0; cb < BUCKETS; cb += 64) {
            int i = cb + tid;
            int orig = (i < BUCKETS) ? hist[i] : 0;
            int x = orig;
            #pragma unroll
            for (int d = 1; d < 64; d <<= 1) {
                int t = __shfl_up(x, d, 64);
                if (tid >= d) x += t;
            }
            int total = __shfl(x, 63, 64);
            if (i < BUCKETS) { start[i] = x - orig + carry; cursor[i] = x - orig + carry; }
            carry += total;
        }
    }
    __syncthreads();

    // parallel global reservations (one atomic per non-empty bucket) --
    // latency hidden under the LDS scatter below
    for (int b = tid; b < BUCKETS; b += 512) {
        int h = hist[b];
        gbase[b] = h ? b * CAP + atomicAdd(&bfill[b], h) : 0;
    }

    // scatter edges into bucket-sorted LDS
    #pragma unroll
    for (int k = 0; k < 16; ++k) {
        int r = rsave[k];
        if (r >= 0) {
            long e = base + (long)k * 512 + tid;
            int pos = atomicAdd(&cursor[r >> 9], 1);
            ebuf[pos] = make_int2(((r & 511) << 18) | cols[e], __float_as_int(vals[e]));
        }
    }
    __syncthreads();

    // burst flush: wave w copies whole slices (contiguous ~224 B) to tmp
    const int wv = tid >> 6, lane = tid & 63;
    const int* eb32 = (const int*)ebuf;
    int* gtmp = (int*)tmp;
    for (int b = wv; b < BUCKETS; b += 8) {
        int cnt2 = hist[b] * 2;                 // dwords
        if (!cnt2) continue;
        int  s2 = start[b] * 2;
        long d2 = (long)gbase[b] * 2;
        for (int i = lane; i < cnt2; i += 64)
            gtmp[d2 + i] = eb32[s2 + i];
    }
}

// exclusive scan of bucket totals -> bucketBase (single wave)
__global__ void scan_buckets(const int* __restrict__ bfill, int* __restrict__ bucketBase) {
    int lane = threadIdx.x;
    int carry = 0;
    for (int cb = 0; cb < BUCKETS; cb += 64) {
        int i = cb + lane;
        int orig = (i < BUCKETS) ? bfill[i] : 0;
        int x = orig;
        #pragma unroll
        for (int d = 1; d < 64; d <<= 1) {
            int t = __shfl_up(x, d, 64);
            if (lane >= d) x += t;
        }
        int total = __shfl(x, 63, 64);
        if (i < BUCKETS) bucketBase[i] = x - orig + carry;
        carry += total;
    }
}

// Pass B: one block per bucket. LDS 512-row histogram + scan -> rowPtr,
// then scatter into the bucket's contiguous csr window (~131 KB, L2-dense).
__global__ void __launch_bounds__(512) binB_kernel(const int* __restrict__ bfill,
                                                   const int* __restrict__ bucketBase,
                                                   const int2* __restrict__ tmp,
                                                   int* __restrict__ rowPtr,
                                                   int2* __restrict__ csr) {
    const int bucket = blockIdx.x;
    __shared__ int lhist[BROWS];
    __shared__ int rp[BROWS];
    __shared__ int fill[BROWS];
    const int t = threadIdx.x;
    lhist[t] = 0; fill[t] = 0;
    __syncthreads();

    const int cnt = bfill[bucket];
    const int2* src = tmp + (long)bucket * CAP;
    for (int k = t; k < cnt; k += 512)
        atomicAdd(&lhist[src[k].x >> 18], 1);
    __syncthreads();

    const int gb = bucketBase[bucket];
    if (t < 64) {
        int carry = 0;
        for (int cb = 0; cb < BROWS; cb += 64) {
            int i = cb + t;
            int orig = lhist[i];
            int x = orig;
            #pragma unroll
            for (int d = 1; d < 64; d <<= 1) {
                int tt = __shfl_up(x, d, 64);
                if (t >= d) x += tt;
            }
            int total = __shfl(x, 63, 64);
            rp[i] = x - orig + carry + gb;     // global exclusive offset
            carry += total;
        }
    }
    __syncthreads();

    int rowIdx = bucket * BROWS + t;           // max 150015; covers rowPtr[150000]
    rowPtr[rowIdx] = rp[t];

    for (int k = t; k < cnt; k += 512) {
        int2 p = src[k];
        int rL = p.x >> 18;
        int pos = rp[rL] + atomicAdd(&fill[rL], 1);
        csr[pos] = make_int2(p.x & 0x3FFFF, p.y);
    }
}

#define ACCX(V, X) { \
    a[0] += (V) * __uint_as_float((X).x << 16); \
    a[1] += (V) * __uint_as_float((X).x & 0xFFFF0000u); \
    a[2] += (V) * __uint_as_float((X).y << 16); \
    a[3] += (V) * __uint_as_float((X).y & 0xFFFF0000u); \
    a[4] += (V) * __uint_as_float((X).z << 16); \
    a[5] += (V) * __uint_as_float((X).z & 0xFFFF0000u); \
    a[6] += (V) * __uint_as_float((X).w << 16); \
    a[7] += (V) * __uint_as_float((X).w & 0xFFFF0000u); }

// --- SpMM: 8 lanes per row, each lane owns 8 bf16 dims (one uint4 gather) --
__global__ void spmm_csr(const int* __restrict__ rowPtr, const int2* __restrict__ csr,
                         const u16* __restrict__ cur, u16* __restrict__ nxt) {
    int gtid = blockIdx.x * blockDim.x + threadIdx.x;
    int row = gtid >> 3;
    int t   = gtid & 7;
    if (row >= NNODES) return;
    int beg = rowPtr[row], end = rowPtr[row + 1];
    float a[8];
    #pragma unroll
    for (int i = 0; i < 8; ++i) a[i] = 0.f;

    int e = beg;
    for (; e + 7 < end; e += 8) {            // 8 outstanding gathers
        int2 p[8];
        #pragma unroll
        for (int j = 0; j < 8; ++j) p[j] = csr[e + j];
        uint4 x[8];
        #pragma unroll
        for (int j = 0; j < 8; ++j)
            x[j] = *(const uint4*)(cur + ((long)p[j].x << 6) + (t << 3));
        #pragma unroll
        for (int j = 0; j < 8; ++j) {
            float v = __int_as_float(p[j].y);
            ACCX(v, x[j]);
        }
    }
    for (; e < end; ++e) {
        int2 p = csr[e];
        float v = __int_as_float(p.y);
        uint4 x = *(const uint4*)(cur + ((long)p.x << 6) + (t << 3));
        ACCX(v, x);
    }

    uint4 o;
    o.x = pack2(a[0], a[1]);
    o.y = pack2(a[2], a[3]);
    o.z = pack2(a[4], a[5]);
    o.w = pack2(a[6], a[7]);
    *(uint4*)(nxt + ((long)row << 6) + (t << 3)) = o;
}

// Layer 3 only at sampled rows: slot s<B -> users[s]; s<2B -> pos; s<3B -> neg.
// Output fp32 [NSAMP][64].
__global__ void spmm_sampled(const int* __restrict__ users,
                             const int* __restrict__ pos_items,
                             const int* __restrict__ neg_items,
                             const int* __restrict__ rowPtr, const int2* __restrict__ csr,
                             const u16* __restrict__ cur, float* __restrict__ sampled) {
    int gtid = blockIdx.x * blockDim.x + threadIdx.x;
    int slot = gtid >> 3;
    int t    = gtid & 7;
    if (slot >= NSAMP) return;
    int row;
    if (slot < BATCH)          row = users[slot];
    else if (slot < 2 * BATCH) row = pos_items[slot - BATCH] + NUM_USERS;
    else                       row = neg_items[slot - 2 * BATCH] + NUM_USERS;

    int beg = rowPtr[row], end = rowPtr[row + 1];
    float a[8];
    #pragma unroll
    for (int i = 0; i < 8; ++i) a[i] = 0.f;

    int e = beg;
    for (; e + 7 < end; e += 8) {
        int2 p[8];
        #pragma unroll
        for (int j = 0; j < 8; ++j) p[j] = csr[e + j];
        uint4 x[8];
        #pragma unroll
        for (int j = 0; j < 8; ++j)
            x[j] = *(const uint4*)(cur + ((long)p[j].x << 6) + (t << 3));
        #pragma unroll
        for (int j = 0; j < 8; ++j) {
            float v = __int_as_float(p[j].y);
            ACCX(v, x[j]);
        }
    }
    for (; e < end; ++e) {
        int2 p = csr[e];
        float v = __int_as_float(p.y);
        uint4 x = *(const uint4*)(cur + ((long)p.x << 6) + (t << 3));
        ACCX(v, x);
    }

    float4* dst = (float4*)(sampled + ((long)slot << 6) + (t << 3));
    dst[0] = make_float4(a[0], a[1], a[2], a[3]);
    dst[1] = make_float4(a[4], a[5], a[6], a[7]);
}

// One wave per batch element; lane = embedding dim.
// final = (emb + l1 + l2 + l3)/4 -> dot scaled by 1/16. l3 from sampled buf.
__global__ void score_kernel(const int* __restrict__ users,
                             const int* __restrict__ pos_items,
                             const int* __restrict__ neg_items,
                             const float* __restrict__ uemb,
                             const float* __restrict__ iemb,
                             const u16* __restrict__ l1,
                             const u16* __restrict__ l2,
                             const float* __restrict__ sampled,
                             float* __restrict__ out) {
    int gtid = blockIdx.x * blockDim.x + threadIdx.x;
    int wave = gtid >> 6;
    int lane = threadIdx.x & 63;
    if (wave >= BATCH) return;
    int u = users[wave];
    int p = pos_items[wave];
    int n = neg_items[wave];
    long U = (long)u * EMB + lane;
    long P = (long)(p + NUM_USERS) * EMB + lane;
    long N = (long)(n + NUM_USERS) * EMB + lane;
    float ue = uemb[(long)u * EMB + lane] + bf2f(l1[U]) + bf2f(l2[U])
             + sampled[(long)wave * EMB + lane];
    float pe = iemb[(long)p * EMB + lane] + bf2f(l1[P]) + bf2f(l2[P])
             + sampled[(long)(BATCH + wave) * EMB + lane];
    float ne = iemb[(long)n * EMB + lane] + bf2f(l1[N]) + bf2f(l2[N])
             + sampled[(long)(2 * BATCH + wave) * EMB + lane];
    float ps = ue * pe;
    float ns = ue * ne;
    #pragma unroll
    for (int off = 32; off > 0; off >>= 1) {
        ps += __shfl_down(ps, off, 64);
        ns += __shfl_down(ns, off, 64);
    }
    if (lane == 0) {
        out[wave]         = ps * 0.0625f;
        out[BATCH + wave] = ns * 0.0625f;
    }
}

extern "C" void kernel_launch(void* const* d_in, const int* in_sizes, int n_in,
                              void* d_out, int out_size, void* d_ws, size_t ws_size,
                              hipStream_t stream) {
    const int*   users = (const int*)d_in[0];
    const int*   pos   = (const int*)d_in[1];
    const int*   neg   = (const int*)d_in[2];
    const int*   rows  = (const int*)d_in[3];
    const int*   cols  = (const int*)d_in[4];
    const float* vals  = (const float*)d_in[5];
    const float* uemb  = (const float*)d_in[6];
    const float* iemb  = (const float*)d_in[7];
    float* out = (float*)d_out;

    const size_t tblElems = (size_t)NNODES * EMB;       // bf16 elems, 19.2 MB each
    u16*  B0      = (u16*)d_ws;                         // l0
    u16*  B1      = B0 + tblElems;                      // l1
    u16*  B2      = B1 + tblElems;                      // l2
    int2* tmp     = (int2*)(B2 + tblElems);             // BUCKETS*CAP int2 = 40.8 MB
    int2* csr     = (int2*)(tmp + (size_t)BUCKETS * CAP);   // NEDGES int2 = 38.4 MB
    int*  rowPtr  = (int*)(csr + NEDGES);               // 150016 ints
    int*  bfill   = rowPtr + 150016;                    // pad 320
    int*  bucketB = bfill + 320;                        // pad 320
    float* sampled= (float*)(bucketB + 320);            // NSAMP*64 fp32 = 3.1 MB
    // total ~140 MB (r2 used ~155 MB successfully)

    hipMemsetAsync(bfill, 0, 320 * sizeof(int), stream);

    // CSR build: LDS-sort + burst flush -> bucket scan -> per-bucket resolve
    binA_kernel<<<NBLK_A, 512, 0, stream>>>(rows, cols, vals, bfill, tmp);
    scan_buckets<<<1, 64, 0, stream>>>(bfill, bucketB);
    binB_kernel<<<BUCKETS, 512, 0, stream>>>(bfill, bucketB, tmp, rowPtr, csr);

    // init l0 (bf16)
    const long n4 = (long)tblElems / 4;
    init_kernel<<<(int)((n4 + 255) / 256), 256, 0, stream>>>(uemb, iemb, B0);

    // layers 1,2 full; layer 3 only at sampled rows
    const long nth = (long)NNODES * 8;
    const int  spmmGrid = (int)((nth + 255) / 256);
    spmm_csr<<<spmmGrid, 256, 0, stream>>>(rowPtr, csr, B0, B1);
    spmm_csr<<<spmmGrid, 256, 0, stream>>>(rowPtr, csr, B1, B2);
    spmm_sampled<<<(NSAMP * 8 + 255) / 256, 256, 0, stream>>>(users, pos, neg,
                                                              rowPtr, csr, B2, sampled);

    score_kernel<<<(BATCH * 64) / 256, 256, 0, stream>>>(users, pos, neg,
                                                         uemb, iemb, B1, B2, sampled, out);
}